// Round 1
// baseline (64.712 us; speedup 1.0000x reference)
//
#include <hip/hip_runtime.h>
#include <math.h>

// Problem constants (from reference): x is (2,2,1,80,80) f32 -> B=4 images 80x80.
#define BATCH 4
#define H 80
#define W 80
#define R 7
#define L 49
#define PAD 3            // R/2
#define TILES_X 40       // 2x2 output tiles per row
#define TILES 1600       // 40*40 per image

typedef float v2f __attribute__((ext_vector_type(2)));

__device__ __forceinline__ float clamp255(float v) {
    return fminf(fmaxf(v, 0.0f), 255.0f);
}

#define KSCALE 0.33972871239731236f   // sqrt(0.08 * log2(e))

// ---------------------------------------------------------------------------
// Kernel 1: per-pixel unsharp-mask "division" value, computed ONCE per pixel
// (the fused kernel recomputed it ~16x: 8x8 union on stride-2 tiles).
// Arithmetic chain is verbatim from the fused kernel's stage 1 — the 25 f32
// blur addends accumulate in f64 in the identical dy/dx order, then the same
// rintf/clamp/divide chain, then the same KSCALE multiply. Bit-exact.
// Writes u = division * KSCALE (the value stage 2 consumes directly).
// ---------------------------------------------------------------------------
__global__ void division_kernel(const float* __restrict__ x, float* __restrict__ u) {
    int t = blockIdx.x * blockDim.x + threadIdx.x;
    if (t >= BATCH * H * W) return;
    int b   = t / (H * W);
    int rem = t - b * (H * W);
    int iy  = rem / W;
    int ix  = rem - iy * W;
    const float* img = x + b * H * W;

    double s = 0.0;
    float xv = 0.0f;
    #pragma unroll
    for (int dy = -2; dy <= 2; ++dy) {
        int yy = iy + dy;
        bool yok = (yy >= 0) & (yy < H);
        #pragma unroll
        for (int dx = -2; dx <= 2; ++dx) {
            int xx = ix + dx;
            if (yok && xx >= 0 && xx < W) {
                float v = img[yy * W + xx];
                if (dy == 0 && dx == 0) xv = v;
                s += (double)v;
            }
        }
    }
    float smooth = rintf((float)(s / 25.0));
    float sharp  = rintf(clamp255(__fsub_rn(__fmul_rn(2.5f, xv), __fmul_rn(1.25f, smooth))));
    float dv     = rintf(clamp255(__fdiv_rn(__fmul_rn(sharp, 255.0f), __fadd_rn(smooth, 1e-8f))));
    u[t] = dv * KSCALE;
}

// ---------------------------------------------------------------------------
// Kernel 2: one wave per 2x2 output tile. Stage 1 is now a single f32 load of
// the precomputed u value (clamped coords at image edges, as before — clamped
// lanes only feed discarded border outputs). Stage 2 (all-pairs KDE over the
// 8x8 union, compile-time patch membership, pk-paired accumulates) and the
// epilogue are byte-identical to the previous fused kernel — accumulation
// order of every patch sum is preserved, so the output is bit-identical.
// ---------------------------------------------------------------------------
__global__ void entropy_kernel(const float* __restrict__ u, float* __restrict__ out) {
    const float PSCALE = 1.0f / (49.0f * 6.266570686577501f); // 1/(49*sqrt(2*pi*b^2))
    const float EPS    = 1e-8f;
    const float LN2_49 = 0.6931471805599453f / 49.0f;

    int gtid = blockIdx.x * blockDim.x + threadIdx.x;
    int wave = gtid >> 6;
    int lane = threadIdx.x & 63;
    if (wave >= BATCH * TILES) return;

    int b   = wave / TILES;
    int rem = wave % TILES;
    int ty  = rem / TILES_X;
    int tx  = rem % TILES_X;
    int oy0 = 2 * ty;
    int ox0 = 2 * tx;

    int lr = lane >> 3;          // row in 8x8 tile
    int lc = lane & 7;           // col in 8x8 tile
    int iy = oy0 - PAD + lr;  iy = iy < 0 ? 0 : (iy > H - 1 ? H - 1 : iy);
    int ix = ox0 - PAD + lc;  ix = ix < 0 ? 0 : (ix > W - 1 ? W - 1 : ix);

    // ---- Stage 1 (collapsed): load the precomputed u = division * KSCALE.
    float uu = u[b * H * W + iy * W + ix];

    // ---- Stage 2: all-pairs exp2, shared across the 4 patches.
    v2f aA = {0.0f, 0.0f};   // {a00, a01}
    v2f aB = {0.0f, 0.0f};   // {a10, a11}
    #pragma unroll
    for (int j = 0; j < 64; ++j) {
        float uj = __uint_as_float(__builtin_amdgcn_readlane(__float_as_uint(uu), j));
        float d  = uu - uj;
        float e  = __builtin_amdgcn_exp2f(-(d * d));
        const int rj = j >> 3, cj = j & 7;           // compile-time after unroll
        const bool m00 = (rj < 7) && (cj < 7);
        const bool m01 = (rj < 7) && (cj >= 1);
        const bool m10 = (rj >= 1) && (cj < 7);
        const bool m11 = (rj >= 1) && (cj >= 1);
        if (m00 && m01)      { v2f ee = {e, e}; aA += ee; }
        else if (m00)        aA.x += e;
        else if (m01)        aA.y += e;
        if (m10 && m11)      { v2f ee = {e, e}; aB += ee; }
        else if (m10)        aB.x += e;
        else if (m11)        aB.y += e;
    }

    // ---- Epilogue: per-pixel log terms, butterfly sums over the wave.
    float t00 = (lr < 7 && lc < 7)  ? __builtin_amdgcn_logf(fmaf(aA.x, PSCALE, EPS)) : 0.0f;
    float t01 = (lr < 7 && lc >= 1) ? __builtin_amdgcn_logf(fmaf(aA.y, PSCALE, EPS)) : 0.0f;
    float t10 = (lr >= 1 && lc < 7) ? __builtin_amdgcn_logf(fmaf(aB.x, PSCALE, EPS)) : 0.0f;
    float t11 = (lr >= 1 && lc >= 1)? __builtin_amdgcn_logf(fmaf(aB.y, PSCALE, EPS)) : 0.0f;
    #pragma unroll
    for (int off = 32; off; off >>= 1) {
        t00 += __shfl_xor(t00, off, 64);
        t01 += __shfl_xor(t01, off, 64);
        t10 += __shfl_xor(t10, off, 64);
        t11 += __shfl_xor(t11, off, 64);
    }

    if (lane == 0) {
        float* outb = out + b * H * W;
        int oy1 = oy0 + 1, ox1 = ox0 + 1;
        bool iy0ok = (oy0 >= PAD) && (oy0 < H - PAD);
        bool iy1ok = (oy1 >= PAD) && (oy1 < H - PAD);
        bool ix0ok = (ox0 >= PAD) && (ox0 < W - PAD);
        bool ix1ok = (ox1 >= PAD) && (ox1 < W - PAD);
        float2 row0, row1;
        row0.x = (iy0ok && ix0ok) ? -t00 * LN2_49 : 0.0f;
        row0.y = (iy0ok && ix1ok) ? -t01 * LN2_49 : 0.0f;
        row1.x = (iy1ok && ix0ok) ? -t10 * LN2_49 : 0.0f;
        row1.y = (iy1ok && ix1ok) ? -t11 * LN2_49 : 0.0f;
        *(float2*)(outb + oy0 * W + ox0) = row0;   // W even, ox0 even -> 8B aligned
        *(float2*)(outb + oy1 * W + ox0) = row1;
    }
}

extern "C" void kernel_launch(void* const* d_in, const int* in_sizes, int n_in,
                              void* d_out, int out_size, void* d_ws, size_t ws_size,
                              hipStream_t stream) {
    const float* x = (const float*)d_in[0];
    float* out = (float*)d_out;
    float* uimg = (float*)d_ws;   // 4*80*80 f32 = 102400 B, well within ws

    // Kernel 1: 25600 pixels, one thread each (400 waves) — per-pixel division.
    division_kernel<<<(BATCH * H * W + 255) / 256, 256, 0, stream>>>(x, uimg);
    // Kernel 2: one wave per 2x2 tile: 4*1600 = 6400 waves -> 1600 blocks of 256.
    entropy_kernel<<<(BATCH * TILES * 64 + 255) / 256, 256, 0, stream>>>(uimg, out);
}

// Round 2
// 61.623 us; speedup vs baseline: 1.0501x; 1.0501x over previous
//
#include <hip/hip_runtime.h>
#include <math.h>

// Problem constants (from reference): x is (2,2,1,80,80) f32 -> B=4 images 80x80.
#define BATCH 4
#define H 80
#define W 80
#define R 7
#define L 49
#define PAD 3            // R/2
#define TILES_X 40       // 2x2 output tiles per row
#define TILES 1600       // 40*40 per image

typedef float v2f __attribute__((ext_vector_type(2)));

__device__ __forceinline__ float clamp255(float v) {
    return fminf(fmaxf(v, 0.0f), 255.0f);
}

// Fully fused kernel: one wave per 2x2 output tile; no scratch buffer.
// (R1 post-mortem: a split precompute kernel LOST 2.4us — dispatch overhead
// exceeds the entire stage-1 savings. This problem is dispatch-count-bound.)
// Lane (lr,lc) of the 8x8 grid owns image pixel (oy0-3+lr, ox0-3+lc).
// NEW vs R0 baseline: wave-uniform interior fast path. For ty,tx in [3,36]
// (72% of waves) the 12x12 blur footprint is statically in-bounds, so the
// per-tap bounds checks and lane-coordinate clamps vanish. Identical f64
// accumulation order => bit-identical results on both paths.
__global__ void entropy_fused_kernel(const float* __restrict__ x, float* __restrict__ out) {
    const float KSCALE = 0.33972871239731236f;    // sqrt(0.08 * log2(e))
    const float PSCALE = 1.0f / (49.0f * 6.266570686577501f); // 1/(49*sqrt(2*pi*b^2))
    const float EPS    = 1e-8f;
    const float LN2_49 = 0.6931471805599453f / 49.0f;

    int gtid = blockIdx.x * blockDim.x + threadIdx.x;
    int wave = gtid >> 6;
    int lane = threadIdx.x & 63;
    if (wave >= BATCH * TILES) return;

    int b   = wave / TILES;
    int rem = wave % TILES;
    int ty  = rem / TILES_X;
    int tx  = rem % TILES_X;
    int oy0 = 2 * ty;
    int ox0 = 2 * tx;

    int lr = lane >> 3;          // row in 8x8 tile
    int lc = lane & 7;           // col in 8x8 tile

    const float* img = x + b * H * W;

    // ---- Stage 1: division value for this lane's pixel. Blur sum in double:
    // the 25 f32 addends are exact in f64, so s is EXACT; s/25.0 correctly
    // rounded; then the same rintf/clamp chain (absmax 0.0 through R1).
    double s = 0.0;
    float xv = 0.0f;
    // Wave-uniform interior test: footprint rows [oy0-5, oy0+6], cols
    // [ox0-5, ox0+6] all in [0,79]  <=>  oy0,ox0 in [6,72] (even) <=> ty,tx in [3,36].
    if (ty >= 3 && ty <= 36 && tx >= 3 && tx <= 36) {
        // FAST PATH (72% of waves): no clamps, no per-tap guards.
        int iy = oy0 - PAD + lr;
        int ix = ox0 - PAD + lc;
        const float* p = img + iy * W + ix;
        #pragma unroll
        for (int dy = -2; dy <= 2; ++dy) {
            #pragma unroll
            for (int dx = -2; dx <= 2; ++dx) {
                float v = p[dy * W + dx];
                if (dy == 0 && dx == 0) xv = v;
                s += (double)v;
            }
        }
    } else {
        // GUARDED PATH: identical to R0 baseline (clamped lane coords feed
        // only discarded border outputs; zero-padded 5x5 blur).
        int iy = oy0 - PAD + lr;  iy = iy < 0 ? 0 : (iy > H - 1 ? H - 1 : iy);
        int ix = ox0 - PAD + lc;  ix = ix < 0 ? 0 : (ix > W - 1 ? W - 1 : ix);
        #pragma unroll
        for (int dy = -2; dy <= 2; ++dy) {
            int yy = iy + dy;
            bool yok = (yy >= 0) & (yy < H);
            #pragma unroll
            for (int dx = -2; dx <= 2; ++dx) {
                int xx = ix + dx;
                if (yok && xx >= 0 && xx < W) {
                    float v = img[yy * W + xx];
                    if (dy == 0 && dx == 0) xv = v;
                    s += (double)v;
                }
            }
        }
    }
    float smooth = rintf((float)(s / 25.0));
    float sharp  = rintf(clamp255(__fsub_rn(__fmul_rn(2.5f, xv), __fmul_rn(1.25f, smooth))));
    float dv     = rintf(clamp255(__fdiv_rn(__fmul_rn(sharp, 255.0f), __fadd_rn(smooth, 1e-8f))));
    float u      = dv * KSCALE;

    // ---- Stage 2: all-pairs exp2, shared across the 4 patches.
    v2f aA = {0.0f, 0.0f};   // {a00, a01}
    v2f aB = {0.0f, 0.0f};   // {a10, a11}
    #pragma unroll
    for (int j = 0; j < 64; ++j) {
        float uj = __uint_as_float(__builtin_amdgcn_readlane(__float_as_uint(u), j));
        float d  = u - uj;
        float e  = __builtin_amdgcn_exp2f(-(d * d));
        const int rj = j >> 3, cj = j & 7;           // compile-time after unroll
        const bool m00 = (rj < 7) && (cj < 7);
        const bool m01 = (rj < 7) && (cj >= 1);
        const bool m10 = (rj >= 1) && (cj < 7);
        const bool m11 = (rj >= 1) && (cj >= 1);
        if (m00 && m01)      { v2f ee = {e, e}; aA += ee; }
        else if (m00)        aA.x += e;
        else if (m01)        aA.y += e;
        if (m10 && m11)      { v2f ee = {e, e}; aB += ee; }
        else if (m10)        aB.x += e;
        else if (m11)        aB.y += e;
    }

    // ---- Epilogue: per-pixel log terms, butterfly sums over the wave.
    float t00 = (lr < 7 && lc < 7)  ? __builtin_amdgcn_logf(fmaf(aA.x, PSCALE, EPS)) : 0.0f;
    float t01 = (lr < 7 && lc >= 1) ? __builtin_amdgcn_logf(fmaf(aA.y, PSCALE, EPS)) : 0.0f;
    float t10 = (lr >= 1 && lc < 7) ? __builtin_amdgcn_logf(fmaf(aB.x, PSCALE, EPS)) : 0.0f;
    float t11 = (lr >= 1 && lc >= 1)? __builtin_amdgcn_logf(fmaf(aB.y, PSCALE, EPS)) : 0.0f;
    #pragma unroll
    for (int off = 32; off; off >>= 1) {
        t00 += __shfl_xor(t00, off, 64);
        t01 += __shfl_xor(t01, off, 64);
        t10 += __shfl_xor(t10, off, 64);
        t11 += __shfl_xor(t11, off, 64);
    }

    if (lane == 0) {
        float* outb = out + b * H * W;
        int oy1 = oy0 + 1, ox1 = ox0 + 1;
        bool iy0ok = (oy0 >= PAD) && (oy0 < H - PAD);
        bool iy1ok = (oy1 >= PAD) && (oy1 < H - PAD);
        bool ix0ok = (ox0 >= PAD) && (ox0 < W - PAD);
        bool ix1ok = (ox1 >= PAD) && (ox1 < W - PAD);
        float2 row0, row1;
        row0.x = (iy0ok && ix0ok) ? -t00 * LN2_49 : 0.0f;
        row0.y = (iy0ok && ix1ok) ? -t01 * LN2_49 : 0.0f;
        row1.x = (iy1ok && ix0ok) ? -t10 * LN2_49 : 0.0f;
        row1.y = (iy1ok && ix1ok) ? -t11 * LN2_49 : 0.0f;
        *(float2*)(outb + oy0 * W + ox0) = row0;   // W even, ox0 even -> 8B aligned
        *(float2*)(outb + oy1 * W + ox0) = row1;
    }
}

extern "C" void kernel_launch(void* const* d_in, const int* in_sizes, int n_in,
                              void* d_out, int out_size, void* d_ws, size_t ws_size,
                              hipStream_t stream) {
    const float* x = (const float*)d_in[0];
    float* out = (float*)d_out;
    (void)d_ws; (void)ws_size;   // no scratch: fully fused, single dispatch

    // One wave per 2x2 tile: 4*1600 = 6400 waves -> 1600 blocks of 256
    entropy_fused_kernel<<<(BATCH * TILES * 64 + 255) / 256, 256, 0, stream>>>(x, out);
}